// Round 4
// baseline (52.808 us; speedup 1.0000x reference)
//
#include <hip/hip_runtime.h>

// Problem constants (from reference)
#define IN_F 4096
#define OUT_F 12288
#define GROUPSIZE 128
#define BATCH 8
#define NGROUPS 32

// Tiling
#define CHUNK 256                       // k elements per wave pass (64 lanes x 4)
#define NCHUNKS (IN_F / CHUNK)          // 16
#define ROWS_PER_WAVE 4
#define WAVES_PER_BLOCK 4
#define ROWS_PER_BLOCK (ROWS_PER_WAVE * WAVES_PER_BLOCK)  // 16
#define NBLOCKS (OUT_F / ROWS_PER_BLOCK)                  // 768

__global__ __launch_bounds__(256, 4)
void w4a32_gemv(const float* __restrict__ x,
                const int* __restrict__ qw,
                const float* __restrict__ scales,
                const float* __restrict__ zeros,
                float* __restrict__ out)
{
    __shared__ float xs[BATCH][CHUNK];  // 8 KB

    const int tid  = threadIdx.x;
    const int wave = tid >> 6;
    const int lane = tid & 63;
    const int row0 = blockIdx.x * ROWS_PER_BLOCK + wave * ROWS_PER_WAVE;

    float acc[ROWS_PER_WAVE][BATCH];
#pragma unroll
    for (int r = 0; r < ROWS_PER_WAVE; ++r)
#pragma unroll
        for (int b = 0; b < BATCH; ++b) acc[r][b] = 0.f;

    for (int c = 0; c < NCHUNKS; ++c) {
        const int k0 = c * CHUNK;

        __syncthreads();  // protect xs from previous iteration's readers
        // Stage x[0:8][k0:k0+256] -> LDS. 2048 floats = 512 float4; 256 thr x 2.
#pragma unroll
        for (int h = 0; h < 2; ++h) {
            const int quad = tid + h * 256;        // 0..511
            const int b    = quad >> 6;            // 64 quads (256 floats) per batch row
            const int kk   = (quad & 63) << 2;
            const float4 v = *reinterpret_cast<const float4*>(&x[b * IN_F + k0 + kk]);
            *reinterpret_cast<float4*>(&xs[b][kk]) = v;
        }
        __syncthreads();

        // Each lane's slice of x for this chunk: k = k0 + 4*lane + (0..3)
        float4 xr[BATCH];
#pragma unroll
        for (int b = 0; b < BATCH; ++b)
            xr[b] = *reinterpret_cast<const float4*>(&xs[b][lane << 2]);

        const int g = (k0 >> 7) + (lane >> 5);  // group id for this lane's 4 k's

#pragma unroll
        for (int r = 0; r < ROWS_PER_WAVE; ++r) {
            const int n = row0 + r;
            // 1 KiB contiguous per wave: perfectly coalesced
            const int4 q = *reinterpret_cast<const int4*>(&qw[n * IN_F + k0 + (lane << 2)]);
            const float s  = scales[g * OUT_F + n];   // broadcast within 32-lane half
            const float z  = zeros [g * OUT_F + n];
            const float cc = __builtin_fmaf(s, -8.f, z);  // z - 8*s
            const float w0 = __builtin_fmaf((float)q.x, s, cc);
            const float w1 = __builtin_fmaf((float)q.y, s, cc);
            const float w2 = __builtin_fmaf((float)q.z, s, cc);
            const float w3 = __builtin_fmaf((float)q.w, s, cc);
#pragma unroll
            for (int b = 0; b < BATCH; ++b) {
                float a = acc[r][b];
                a = __builtin_fmaf(w0, xr[b].x, a);
                a = __builtin_fmaf(w1, xr[b].y, a);
                a = __builtin_fmaf(w2, xr[b].z, a);
                a = __builtin_fmaf(w3, xr[b].w, a);
                acc[r][b] = a;
            }
        }
    }

    // Final cross-lane reduction (once per row) + store
#pragma unroll
    for (int r = 0; r < ROWS_PER_WAVE; ++r) {
        const int n = row0 + r;
#pragma unroll
        for (int b = 0; b < BATCH; ++b) {
            float v = acc[r][b];
            v += __shfl_xor(v, 32);
            v += __shfl_xor(v, 16);
            v += __shfl_xor(v, 8);
            v += __shfl_xor(v, 4);
            v += __shfl_xor(v, 2);
            v += __shfl_xor(v, 1);
            if (lane == b) out[b * OUT_F + n] = v;  // lanes 0..7 store the 8 batches
        }
    }
}

extern "C" void kernel_launch(void* const* d_in, const int* in_sizes, int n_in,
                              void* d_out, int out_size, void* d_ws, size_t ws_size,
                              hipStream_t stream) {
    const float* x      = (const float*)d_in[0];
    const int*   qw     = (const int*)d_in[1];
    const float* scales = (const float*)d_in[2];
    const float* zeros  = (const float*)d_in[3];
    float* out = (float*)d_out;

    w4a32_gemv<<<NBLOCKS, 256, 0, stream>>>(x, qw, scales, zeros, out);
}